// Round 1
// baseline (4411.728 us; speedup 1.0000x reference)
//
#include <hip/hip_runtime.h>
#include <hip/hip_fp16.h>
#include <stdint.h>

// ---------------------------------------------------------------------------
// TreeSimpleGRU on MI355X: dependency-driven persistent-worker execution.
//
// Phase 1 (parallel): weight transposes/f16 packing, per-node static GEMMs
//   A[n] (word+tag+bias rows, internal nodes only), R[n] (rel rows, all
//   nodes), leaf K's, group-boundary scan of the edge list.
// Phase 2 (k_worker): persistent workgroups pop parent-groups in edge order
//   (descending parent = topological), spin on agent-scope ready flags,
//   keep U and W_k weights in VGPRs (f16 pairs, v_dot2), absorb
//   single-child parent chains locally (no global handoff).
// ---------------------------------------------------------------------------

#define ROWS 470      // 450 GRU rows + 20 attention rows
#define AST  480      // A_all / R_all row stride (halves)
#define WST  512      // UW / WK column stride (uint32 words), cols >=470 zero
#define KST  96       // K_pack stride in words (384 B = 3 x 128B lines)
#define NPAIR 75      // 150 halves / 2

static __device__ __forceinline__ float fdot2f(uint32_t w, uint32_t x, float acc){
#if __has_builtin(__builtin_amdgcn_fdot2)
  typedef _Float16 h2v __attribute__((ext_vector_type(2)));
  return __builtin_amdgcn_fdot2(__builtin_bit_cast(h2v,w), __builtin_bit_cast(h2v,x), acc, false);
#else
  __half2 a = __builtin_bit_cast(__half2,w), b = __builtin_bit_cast(__half2,x);
  return acc + __low2float(a)*__low2float(b) + __high2float(a)*__high2float(b);
#endif
}
static __device__ __forceinline__ float sigm(float x){ return 1.f/(1.f+__expf(-x)); }
static __device__ __forceinline__ float tanhx(float x){ float e=__expf(2.f*x); return 1.f - 2.f/(e+1.f); }
static __device__ __forceinline__ uint32_t packh(float a, float b){
  return (uint32_t)__half_as_ushort(__float2half(a)) | ((uint32_t)__half_as_ushort(__float2half(b))<<16);
}

// ---------------------------------------------------------------------------
// K1: weight transposes / packing + per-edge scatter (parent_of, has_child)
// ---------------------------------------------------------------------------
__global__ void k_prep(const int* __restrict__ edges, int E,
                       const float* __restrict__ node_U, const float* __restrict__ node_W,
                       const float* __restrict__ at_Wb,  const float* __restrict__ leaf_W,
                       uint32_t* __restrict__ UW, uint32_t* __restrict__ WK,
                       float* __restrict__ NWT, float* __restrict__ LWT, float* __restrict__ RWT,
                       int* __restrict__ parent_of, int* __restrict__ has_child)
{
  int o = blockIdx.x*blockDim.x + threadIdx.x;
  if (o < E) {
    int p = edges[2*o], c = edges[2*o+1];
    parent_of[c] = p; has_child[p] = 1;
    if (o == 0) parent_of[0] = -1;
    return;
  }
  o -= E;
  if (o < NPAIR*WST) {             // UW: packed f16 pairs of node_U, [i][row]
    int i = o/WST, j = o%WST;
    uint32_t v = 0u;
    if (j < 450) v = packh(node_U[j*150 + 2*i], node_U[j*150 + 2*i + 1]);
    UW[o] = v; return;
  }
  o -= NPAIR*WST;
  if (o < NPAIR*WST) {             // WK: packed W_k rows (x cols 300..449) + attention rows
    int i = o/WST, j = o%WST;
    uint32_t v = 0u;
    if (j < 450)      v = packh(node_W[j*490 + 300 + 2*i], node_W[j*490 + 301 + 2*i]);
    else if (j < 470) v = packh(at_Wb[(j-450)*490 + 300 + 2*i], at_Wb[(j-450)*490 + 301 + 2*i]);
    WK[o] = v; return;
  }
  o -= NPAIR*WST;
  if (o < 320*ROWS) {              // NWT[i][r]: word(0..299)+tag(->cols 470..489)
    int i = o/ROWS, r = o%ROWS;
    int col = (i < 300) ? i : 470 + (i - 300);
    NWT[o] = (r < 450) ? node_W[r*490 + col] : at_Wb[(r-450)*490 + col];
    return;
  }
  o -= 320*ROWS;
  if (o < 320*450) {               // LWT[i][r]: leaf_W transposed
    int i = o/450, r = o%450;
    LWT[o] = leaf_W[r*320 + i];
    return;
  }
  o -= 320*450;
  if (o < 20*ROWS) {               // RWT[i][r]: rel cols 450..469
    int i = o/ROWS, r = o%ROWS;
    RWT[o] = (r < 450) ? node_W[r*490 + 450 + i] : at_Wb[(r-450)*490 + 450 + i];
    return;
  }
}

// ---------------------------------------------------------------------------
// K1b: uh_leaf[450] = leaf_U @ leaf_h + leaf_b (shared by every leaf)
// ---------------------------------------------------------------------------
__global__ void k_uhleaf(const float* __restrict__ leaf_U, const float* __restrict__ leaf_h,
                         const float* __restrict__ leaf_b, float* __restrict__ uh_leaf)
{
  int t = threadIdx.x;
  if (t < 450) {
    float s = leaf_b[t];
    for (int n = 0; n < 150; ++n) s += leaf_U[t*150 + n]*leaf_h[n];
    uh_leaf[t] = s;
  }
}

// ---------------------------------------------------------------------------
// K2: single-WG scan of the edge list -> group boundaries (+node_group map)
// groups appear in edge order = descending parent, children ascending.
// ---------------------------------------------------------------------------
__global__ void k_scan(const int* __restrict__ edges, int E,
                       int* __restrict__ group_start, int* __restrict__ ctrl,
                       int* __restrict__ node_group)
{
  __shared__ int warp_cnt[16];
  __shared__ int wbase[16];
  __shared__ int base_s;
  int t = threadIdx.x;                 // 1024
  if (t == 0) base_s = 0;
  __syncthreads();
  for (int chunk = 0; chunk < E; chunk += 1024) {
    int i = chunk + t;
    bool flag = false;
    if (i < E) flag = (i == 0) || (edges[2*(i-1)] != edges[2*i]);
    unsigned long long m = __ballot(flag ? 1 : 0);
    int wave = t >> 6, lane = t & 63;
    if (lane == 0) warp_cnt[wave] = __popcll(m);
    __syncthreads();
    if (t == 0) {
      int run = base_s;
      for (int w = 0; w < 16; ++w) { wbase[w] = run; run += warp_cnt[w]; }
      base_s = run;
    }
    __syncthreads();
    if (flag) {
      int g = wbase[wave] + __popcll(m & ((1ull << lane) - 1ull));
      group_start[g] = i;
    }
    __syncthreads();
  }
  if (t == 0) { ctrl[1] = base_s; group_start[base_s] = E; }
  __syncthreads();
  int NG = base_s;
  for (int g = t; g < NG; g += 1024) node_group[edges[2*group_start[g]]] = g;
}

// ---------------------------------------------------------------------------
// K3: all leaves: K[l] = SimpleGRU(leaf_W, uh_leaf, [w;tag]) ; ready=1
// ---------------------------------------------------------------------------
__global__ void k_leaf(const int* __restrict__ leaf_ids,
                       const float* __restrict__ w_emb, const float* __restrict__ tag_emb,
                       const float* __restrict__ LWT, const float* __restrict__ uh_leaf,
                       const float* __restrict__ leaf_h,
                       uint32_t* __restrict__ K_pack, int* __restrict__ ready, int L)
{
  int base = blockIdx.x*8; if (base >= L) return;
  int cnt = min(8, L - base);
  __shared__ __align__(16) float xs[320*8];
  __shared__ float actl[8*450];
  __shared__ int lid[8];
  __shared__ float lh[150];
  int t = threadIdx.x;                 // 512
  if (t < cnt) lid[t] = leaf_ids[base + t];
  if (t < 150) lh[t] = leaf_h[t];
  __syncthreads();
  for (int idx = t; idx < cnt*320; idx += 512) {
    int nl = idx/320, i = idx%320; int n = lid[nl];
    xs[i*8 + nl] = (i < 300) ? w_emb[(size_t)n*300 + i] : tag_emb[(size_t)n*20 + (i-300)];
  }
  __syncthreads();
  if (t < 450) {
    float a0=0,a1=0,a2=0,a3=0,a4=0,a5=0,a6=0,a7=0;
    for (int i = 0; i < 320; ++i) {
      float w = LWT[i*450 + t];
      const float4* x4 = (const float4*)(xs + i*8);
      float4 xa = x4[0], xb = x4[1];
      a0 += w*xa.x; a1 += w*xa.y; a2 += w*xa.z; a3 += w*xa.w;
      a4 += w*xb.x; a5 += w*xb.y; a6 += w*xb.z; a7 += w*xb.w;
    }
    float acc[8] = {a0,a1,a2,a3,a4,a5,a6,a7};
    float uh = uh_leaf[t];
    for (int j = 0; j < cnt; ++j) {
      float pre = acc[j] + uh;
      actl[j*450 + t] = (t < 300) ? sigm(pre) : tanhx(pre);
    }
  }
  __syncthreads();
  for (int idx = t; idx < cnt*150; idx += 512) {
    int nl = idx/150, m = idx%150;
    float z = actl[nl*450 + m], r = actl[nl*450 + 150 + m], ht = actl[nl*450 + 300 + m];
    float kv = r*lh[m] + (1.f - z)*ht;
    ((__half*)(K_pack + (size_t)lid[nl]*KST))[m] = __float2half(kv);
  }
  __syncthreads();
  if (t < cnt) ready[lid[t]] = 1;
}

// ---------------------------------------------------------------------------
// K4: A_all rows for internal nodes (group parents): W_word@w + W_tag@tag + b
// rows 450..469 = attention (at_Wb word/tag cols + at_bb)
// ---------------------------------------------------------------------------
__global__ void k_static(const int* __restrict__ edges, const int* __restrict__ group_start,
                         const int* __restrict__ ctrl,
                         const float* __restrict__ w_emb, const float* __restrict__ tag_emb,
                         const float* __restrict__ NWT, const float* __restrict__ node_b,
                         const float* __restrict__ at_bb, __half* __restrict__ A_all)
{
  int NG = ctrl[1];
  int base = blockIdx.x*16; if (base >= NG) return;
  int cnt = min(16, NG - base);
  __shared__ __align__(16) float xs[320*16];
  __shared__ int pl[16];
  int t = threadIdx.x;                 // 512
  if (t < cnt) pl[t] = edges[2*group_start[base + t]];
  __syncthreads();
  for (int idx = t; idx < cnt*320; idx += 512) {
    int nl = idx/320, i = idx%320; int n = pl[nl];
    xs[i*16 + nl] = (i < 300) ? w_emb[(size_t)n*300 + i] : tag_emb[(size_t)n*20 + (i-300)];
  }
  __syncthreads();
  if (t < ROWS) {
    float acc[16];
    #pragma unroll
    for (int j = 0; j < 16; ++j) acc[j] = 0.f;
    for (int i = 0; i < 320; ++i) {
      float w = NWT[i*ROWS + t];
      const float4* x4 = (const float4*)(xs + i*16);
      float4 xa = x4[0], xb = x4[1], xc = x4[2], xd = x4[3];
      acc[0]+=w*xa.x; acc[1]+=w*xa.y; acc[2]+=w*xa.z; acc[3]+=w*xa.w;
      acc[4]+=w*xb.x; acc[5]+=w*xb.y; acc[6]+=w*xb.z; acc[7]+=w*xb.w;
      acc[8]+=w*xc.x; acc[9]+=w*xc.y; acc[10]+=w*xc.z; acc[11]+=w*xc.w;
      acc[12]+=w*xd.x; acc[13]+=w*xd.y; acc[14]+=w*xd.z; acc[15]+=w*xd.w;
    }
    float bias = (t < 450) ? node_b[t] : at_bb[t-450];
    for (int j = 0; j < cnt; ++j)
      A_all[(size_t)pl[j]*AST + t] = __float2half(acc[j] + bias);
  }
}

// ---------------------------------------------------------------------------
// K5: R_all rows for all nodes: W_rel@rel (+attention rel rows), no bias
// ---------------------------------------------------------------------------
__global__ void k_rel(const float* __restrict__ rel_emb, const float* __restrict__ RWT_g,
                      __half* __restrict__ R_all, int N)
{
  __shared__ float rw[20*ROWS];
  __shared__ float xs[20*32];
  int t = threadIdx.x;                 // 512
  for (int idx = t; idx < 20*ROWS; idx += 512) rw[idx] = RWT_g[idx];
  int base = blockIdx.x*32;
  int cnt = min(32, N - base);
  for (int idx = t; idx < cnt*20; idx += 512) {
    int nl = idx/20, i = idx%20;
    xs[i*32 + nl] = rel_emb[(size_t)(base+nl)*20 + i];
  }
  __syncthreads();
  if (t < ROWS) {
    float w[20];
    #pragma unroll
    for (int i = 0; i < 20; ++i) w[i] = rw[i*ROWS + t];
    for (int j = 0; j < cnt; ++j) {
      float acc = 0.f;
      #pragma unroll
      for (int i = 0; i < 20; ++i) acc += w[i]*xs[i*32 + j];
      R_all[(size_t)(base+j)*AST + t] = __float2half(acc);
    }
  }
}

// ---------------------------------------------------------------------------
// K6: persistent dependency-driven worker
// ---------------------------------------------------------------------------
__global__ __launch_bounds__(256, 1)
void k_worker(const int* __restrict__ edges,
              const float* __restrict__ at_Wa, const float* __restrict__ at_ba,
              const uint32_t* __restrict__ UW, const uint32_t* __restrict__ WK,
              const __half* __restrict__ A_all, const __half* __restrict__ R_all,
              uint32_t* __restrict__ K_pack, int* __restrict__ ready,
              int* __restrict__ ctrl, const int* __restrict__ group_start,
              const int* __restrict__ parent_of, const int* __restrict__ node_group,
              const int* __restrict__ has_child, float* __restrict__ d_out)
{
  const int t = threadIdx.x;           // 256
  const int rowB = 256 + t;            // rows 256..469 valid for t<214
  const bool hasB = (t < 214);

  __shared__ __align__(16) float    h_f32[152];
  __shared__ __align__(16) uint32_t h_pack[80];
  __shared__ __align__(16) uint32_t kc[80];
  __shared__ float act[472];
  __shared__ float was[20];
  __shared__ int   s_g;

  // register-resident f16-pair weights (cols >= 470 are zero in UW/WK)
  uint32_t uwA[NPAIR], wkA[NPAIR], uwB[NPAIR], wkB[NPAIR];
  #pragma unroll
  for (int i = 0; i < NPAIR; ++i) {
    uwA[i] = UW[i*WST + t];    wkA[i] = WK[i*WST + t];
    uwB[i] = UW[i*WST + rowB]; wkB[i] = WK[i*WST + rowB];
  }
  if (t < 20) was[t] = at_Wa[t];
  const float atba_v = at_ba[0];
  const int NG = ctrl[1];
  int* counter = ctrl;                  // ctrl[0]
  float hreg = 0.f;

  // one GRU_AT edge step. preA/preB already hold static + R + uh terms.
  auto do_step = [&](float preA, float preB, const uint32_t* __restrict__ kcsrc) {
    #pragma unroll
    for (int i = 0; i < 18; ++i) {
      uint4 kk = ((const uint4*)kcsrc)[i];
      preA = fdot2f(wkA[4*i+0], kk.x, preA); preB = fdot2f(wkB[4*i+0], kk.x, preB);
      preA = fdot2f(wkA[4*i+1], kk.y, preA); preB = fdot2f(wkB[4*i+1], kk.y, preB);
      preA = fdot2f(wkA[4*i+2], kk.z, preA); preB = fdot2f(wkB[4*i+2], kk.z, preB);
      preA = fdot2f(wkA[4*i+3], kk.w, preA); preB = fdot2f(wkB[4*i+3], kk.w, preB);
    }
    #pragma unroll
    for (int i = 72; i < NPAIR; ++i) {
      uint32_t kk = kcsrc[i];
      preA = fdot2f(wkA[i], kk, preA); preB = fdot2f(wkB[i], kk, preB);
    }
    float vA = sigm(preA);                              // rows 0..255: z/r gates
    float vB = (t < 44) ? sigm(preB) : tanhx(preB);     // 256..299 sigm, 300..469 tanh
    act[t] = vA;
    if (hasB) act[256 + t] = vB;
    __syncthreads();
    if (t < 150) {
      float s = atba_v;
      #pragma unroll
      for (int j = 0; j < 20; ++j) s += was[j]*act[450 + j];
      float a = sigm(s);
      float z = act[t], r = act[150 + t], ht = act[300 + t];
      float m  = r*hreg + (1.f - z)*ht;
      float hn = a*m + (1.f - a)*hreg;
      hreg = hn;
      h_f32[t] = hn;
      ((__half*)h_pack)[t] = __float2half(hn);
    }
    __syncthreads();
  };

  // U @ h for the next sibling (overlaps the following spin)
  auto calc_uh = [&](float& oA, float& oB) {
    float a0 = 0.f, b0 = 0.f;
    #pragma unroll
    for (int i = 0; i < 18; ++i) {
      uint4 hh = ((const uint4*)h_pack)[i];
      a0 = fdot2f(uwA[4*i+0], hh.x, a0); b0 = fdot2f(uwB[4*i+0], hh.x, b0);
      a0 = fdot2f(uwA[4*i+1], hh.y, a0); b0 = fdot2f(uwB[4*i+1], hh.y, b0);
      a0 = fdot2f(uwA[4*i+2], hh.z, a0); b0 = fdot2f(uwB[4*i+2], hh.z, b0);
      a0 = fdot2f(uwA[4*i+3], hh.w, a0); b0 = fdot2f(uwB[4*i+3], hh.w, b0);
    }
    #pragma unroll
    for (int i = 72; i < NPAIR; ++i) {
      uint32_t hh = h_pack[i];
      a0 = fdot2f(uwA[i], hh, a0); b0 = fdot2f(uwB[i], hh, b0);
    }
    oA = a0; oB = b0;
  };

  for (;;) {
    if (t == 0) s_g = atomicAdd(counter, 1);
    __syncthreads();
    const int g = s_g;
    if (g >= NG) break;
    const int gs = group_start[g], ge = group_start[g+1];
    const int p  = edges[2*gs];
    if (ge - gs == 1) {
      const int c0 = edges[2*gs + 1];
      if (has_child[c0]) continue;     // absorbed: produced by the child's chain
    }
    // ---- group task: process children ascending ----
    if (t < 150) hreg = 0.f;
    float uhA = 0.f, uhB = 0.f;
    const float aStA = __half2float(A_all[(size_t)p*AST + t]);
    const float aStB = __half2float(A_all[(size_t)p*AST + rowB]);
    for (int e = gs; e < ge; ++e) {
      const int c = edges[2*e + 1];
      const float rStA = __half2float(R_all[(size_t)c*AST + t]);
      const float rStB = __half2float(R_all[(size_t)c*AST + rowB]);
      if (t == 0) {
        long spins = 0;
        while (__hip_atomic_load(&ready[c], __ATOMIC_RELAXED, __HIP_MEMORY_SCOPE_AGENT) == 0) {
          __builtin_amdgcn_s_sleep(2);
          if (++spins > 200000000L) break;     // safety valve (never hit if logic sound)
        }
      }
      __syncthreads();
      if (t < NPAIR) kc[t] = __hip_atomic_load(&K_pack[(size_t)c*KST + t],
                                               __ATOMIC_RELAXED, __HIP_MEMORY_SCOPE_AGENT);
      __syncthreads();
      do_step(aStA + rStA + uhA, aStB + rStB + uhB, kc);
      if (e + 1 < ge) calc_uh(uhA, uhB); else { uhA = 0.f; uhB = 0.f; }
    }
    // ---- climb through single-child ancestors, else publish ----
    int q = p;
    for (;;) {
      if (q == 0) { if (t < 150) d_out[t] = h_f32[t]; break; }
      const int r  = parent_of[q];
      const int gr = node_group[r];
      if (group_start[gr+1] - group_start[gr] != 1) {
        if (t < NPAIR) __hip_atomic_store(&K_pack[(size_t)q*KST + t], h_pack[t],
                                          __ATOMIC_RELAXED, __HIP_MEMORY_SCOPE_AGENT);
        __threadfence();
        __syncthreads();
        if (t == 0) __hip_atomic_store(&ready[q], 1, __ATOMIC_RELEASE, __HIP_MEMORY_SCOPE_AGENT);
        break;
      }
      // absorb edge (r, q): h=0, kc = freshly computed h (in LDS)
      const float aA2 = __half2float(A_all[(size_t)r*AST + t]);
      const float aB2 = __half2float(A_all[(size_t)r*AST + rowB]);
      const float rA2 = __half2float(R_all[(size_t)q*AST + t]);
      const float rB2 = __half2float(R_all[(size_t)q*AST + rowB]);
      if (t < 150) hreg = 0.f;
      do_step(aA2 + rA2, aB2 + rB2, h_pack);
      q = r;
    }
  }
}

// ---------------------------------------------------------------------------
extern "C" void kernel_launch(void* const* d_in, const int* in_sizes, int n_in,
                              void* d_out, int out_size, void* d_ws, size_t ws_size,
                              hipStream_t stream)
{
  const float* w_emb   = (const float*)d_in[0];
  const float* tag_emb = (const float*)d_in[1];
  const float* rel_emb = (const float*)d_in[2];
  const float* leaf_h  = (const float*)d_in[3];
  const float* leaf_W  = (const float*)d_in[4];
  const float* leaf_U  = (const float*)d_in[5];
  const float* leaf_b  = (const float*)d_in[6];
  const float* node_W  = (const float*)d_in[7];
  const float* node_U  = (const float*)d_in[8];
  const float* node_b  = (const float*)d_in[9];
  const float* at_Wb   = (const float*)d_in[10];
  const float* at_bb   = (const float*)d_in[11];
  const float* at_Wa   = (const float*)d_in[12];
  const float* at_ba   = (const float*)d_in[13];
  const int*   edges   = (const int*)d_in[14];
  const int*   leaf_ids= (const int*)d_in[15];
  float* out = (float*)d_out;

  const int N = in_sizes[0]/300;
  const int E = in_sizes[14]/2;
  const int L = in_sizes[15];

  char* ws = (char*)d_ws;
  size_t off = 0;
  auto take = [&](size_t bytes) -> char* {
    char* p = ws + off;
    off = (off + bytes + 255) & ~(size_t)255;
    return p;
  };
  // zero region (one memset): ctrl[2] + ready[N] + has_child[N], contiguous
  size_t zbytes = 256 + (size_t)4*N + (size_t)4*N;
  char* zbase       = take(zbytes);
  int*  ctrl        = (int*)zbase;             // [0]=pop counter, [1]=n_groups
  int*  ready       = (int*)(zbase + 256);
  int*  has_child   = (int*)(zbase + 256 + (size_t)4*N);
  int*  parent_of   = (int*)take((size_t)4*N);
  int*  node_group  = (int*)take((size_t)4*N);
  int*  group_start = (int*)take((size_t)4*(N+1));
  uint32_t* UW      = (uint32_t*)take((size_t)4*NPAIR*WST);
  uint32_t* WK      = (uint32_t*)take((size_t)4*NPAIR*WST);
  float* NWT        = (float*)take((size_t)4*320*ROWS);
  float* LWT        = (float*)take((size_t)4*320*450);
  float* RWT        = (float*)take((size_t)4*20*ROWS);
  float* uh_leaf    = (float*)take((size_t)4*456);
  __half* A_all     = (__half*)take((size_t)2*((size_t)N*AST + 64));
  __half* R_all     = (__half*)take((size_t)2*((size_t)N*AST + 64));
  uint32_t* K_pack  = (uint32_t*)take((size_t)4*(size_t)N*KST);
  (void)ws_size; (void)n_in; (void)out_size;

  hipMemsetAsync(zbase, 0, zbytes, stream);

  const int TOT = E + NPAIR*WST + NPAIR*WST + 320*ROWS + 320*450 + 20*ROWS;
  k_prep<<<(TOT + 255)/256, 256, 0, stream>>>(edges, E, node_U, node_W, at_Wb, leaf_W,
                                              UW, WK, NWT, LWT, RWT, parent_of, has_child);
  k_uhleaf<<<1, 512, 0, stream>>>(leaf_U, leaf_h, leaf_b, uh_leaf);
  k_scan<<<1, 1024, 0, stream>>>(edges, E, group_start, ctrl, node_group);
  k_leaf<<<(L + 7)/8, 512, 0, stream>>>(leaf_ids, w_emb, tag_emb, LWT, uh_leaf, leaf_h,
                                        K_pack, ready, L);
  k_static<<<(N + 15)/16, 512, 0, stream>>>(edges, group_start, ctrl, w_emb, tag_emb,
                                            NWT, node_b, at_bb, A_all);
  k_rel<<<(N + 31)/32, 512, 0, stream>>>(rel_emb, RWT, R_all, N);
  k_worker<<<256, 256, 0, stream>>>(edges, at_Wa, at_ba, UW, WK, A_all, R_all,
                                    K_pack, ready, ctrl, group_start, parent_of,
                                    node_group, has_child, out);
}